// Round 1
// baseline (516.405 us; speedup 1.0000x reference)
//
#include <hip/hip_runtime.h>

typedef unsigned short u16;
typedef __bf16 bf16x8 __attribute__((ext_vector_type(8)));
typedef float f32x4 __attribute__((ext_vector_type(4)));
typedef unsigned short u16x8 __attribute__((ext_vector_type(8)));

__device__ __forceinline__ u16 f2bf(float x) {
  union { float f; unsigned int u; } v; v.f = x;
  unsigned int r = v.u + 0x7FFFu + ((v.u >> 16) & 1u);
  return (u16)(r >> 16);
}

__device__ __forceinline__ void gload_lds16(const void* g, void* l) {
  __builtin_amdgcn_global_load_lds(
      (__attribute__((address_space(1))) void*)(g),
      (__attribute__((address_space(3))) void*)(l), 16, 0, 0);
}

// ---------------- fp32 -> bf16 elementwise ----------------
__global__ __launch_bounds__(256) void cvt_bf16(const float* __restrict__ in,
                                                u16* __restrict__ out, int n) {
  int i = (blockIdx.x * 256 + threadIdx.x) * 4;
  if (i + 3 < n) {
    float4 v = *(const float4*)(in + i);
    ushort4 o;
    o.x = f2bf(v.x); o.y = f2bf(v.y); o.z = f2bf(v.z); o.w = f2bf(v.w);
    *(ushort4*)(out + i) = o;
  }
}

// ---------------- W (K x N) -> W^T (N x K) bf16 ----------------
__global__ __launch_bounds__(256) void transpose_cvt(const float* __restrict__ W,
                                                     u16* __restrict__ Wt) {
  const int E = 1024;
  __shared__ float tile[32][33];
  int tx = threadIdx.x & 31, ty = threadIdx.x >> 5;  // 32 x 8
  int bx = blockIdx.x * 32, by = blockIdx.y * 32;
  #pragma unroll
  for (int i = 0; i < 32; i += 8)
    tile[ty + i][tx] = W[(size_t)(by + ty + i) * E + bx + tx];
  __syncthreads();
  #pragma unroll
  for (int i = 0; i < 32; i += 8)
    Wt[(size_t)(bx + ty + i) * E + by + tx] = f2bf(tile[tx][ty + i]);
}

// ---------------- C = A @ Bt^T + bias ----------------
// A: R x K bf16 row-major; Bt: N x K bf16 row-major (i.e. W^T); bias: f32[N]
// m97 structure: 128x128 tile, BK=64, 4 waves (2x2), global_load_lds staging.
template <typename OutT>
__global__ __launch_bounds__(256) void gemm_bt_bias(
    const u16* __restrict__ A, const u16* __restrict__ Bt,
    const float* __restrict__ bias, OutT* __restrict__ C,
    int R, int K, int N)
{
  __shared__ u16 As[128 * 64];
  __shared__ u16 Bs[128 * 64];
  const int tid = threadIdx.x;
  const int w = tid >> 6;
  const int lane = tid & 63;
  const int lo = lane & 15, hi = lane >> 4;
  const int brow = blockIdx.x * 128;
  const int bcol = blockIdx.y * 128;
  const int wr = (w >> 1) * 64;
  const int wc = (w & 1) * 64;

  f32x4 acc[4][4] = {};

  for (int k0 = 0; k0 < K; k0 += 64) {
    __syncthreads();
    #pragma unroll
    for (int i = 0; i < 4; i++) {
      int c = i * 256 + tid;
      int rowo = c >> 3;
      int ko = (c & 7) * 8;
      gload_lds16(A + (size_t)(brow + rowo) * K + k0 + ko,
                  (void*)(As + (size_t)(i * 256 + w * 64) * 8));
      gload_lds16(Bt + (size_t)(bcol + rowo) * K + k0 + ko,
                  (void*)(Bs + (size_t)(i * 256 + w * 64) * 8));
    }
    __syncthreads();
    #pragma unroll
    for (int kk = 0; kk < 2; kk++) {
      bf16x8 af[4], bfr[4];
      #pragma unroll
      for (int mi = 0; mi < 4; mi++)
        af[mi] = *(const bf16x8*)(As + (wr + mi * 16 + lo) * 64 + kk * 32 + hi * 8);
      #pragma unroll
      for (int ni = 0; ni < 4; ni++)
        bfr[ni] = *(const bf16x8*)(Bs + (wc + ni * 16 + lo) * 64 + kk * 32 + hi * 8);
      #pragma unroll
      for (int mi = 0; mi < 4; mi++)
        #pragma unroll
        for (int ni = 0; ni < 4; ni++)
          acc[mi][ni] = __builtin_amdgcn_mfma_f32_16x16x32_bf16(
              af[mi], bfr[ni], acc[mi][ni], 0, 0, 0);
    }
  }

  #pragma unroll
  for (int mi = 0; mi < 4; mi++)
    #pragma unroll
    for (int ni = 0; ni < 4; ni++) {
      int row = brow + wr + mi * 16 + hi * 4;
      int col = bcol + wc + ni * 16 + lo;
      float bv = bias[col];
      #pragma unroll
      for (int r = 0; r < 4; r++) {
        float v = acc[mi][ni][r] + bv;
        if constexpr (sizeof(OutT) == 2)
          C[(size_t)(row + r) * N + col] = (OutT)f2bf(v);
        else
          C[(size_t)(row + r) * N + col] = (OutT)v;
      }
    }
}

// ---------------- flash attention ----------------
// Q/K/V projected, bf16, layout [(seq*B + b)*E + h*64 + d]. Per block: 128 Q
// rows of one (b,h); 4 waves x 32 rows. KV tiles of 64 staged in LDS.
__global__ __launch_bounds__(256) void attn_kernel(
    const u16* __restrict__ Qp, const u16* __restrict__ Kp,
    const u16* __restrict__ Vp, u16* __restrict__ O)
{
  constexpr int Bb = 4, E = 1024, Nn = 2048, Dh = 64;
  constexpr int LDK = 72;  // padded row stride: frag reads spread over banks
  constexpr float SCALE = 0.125f;
  __shared__ u16 Ks[64 * LDK];        // [n][d]
  __shared__ u16 Vt[64 * LDK];        // [d][n]  (transposed V tile)
  __shared__ u16 Ps[4][32 * LDK];     // per-wave P tile [m][n]

  const int tid = threadIdx.x;
  const int lane = tid & 63;
  const int w = tid >> 6;
  const int lo = lane & 15, hi = lane >> 4;
  const int b_ = blockIdx.y >> 4, h = blockIdx.y & 15;
  const int mbase = blockIdx.x * 128 + w * 32;

  // Q fragments held in registers for the whole block
  bf16x8 q[2][2];
  #pragma unroll
  for (int mi = 0; mi < 2; mi++)
    #pragma unroll
    for (int kk = 0; kk < 2; kk++) {
      int m = mbase + mi * 16 + lo;
      q[mi][kk] = *(const bf16x8*)(Qp + (size_t)(m * Bb + b_) * E + h * Dh + kk * 32 + hi * 8);
    }

  f32x4 acc[2][4] = {};
  float mrun[2][4], lrun[2][4];
  #pragma unroll
  for (int mi = 0; mi < 2; mi++)
    #pragma unroll
    for (int r = 0; r < 4; r++) { mrun[mi][r] = -1e30f; lrun[mi][r] = 0.f; }

  for (int n0 = 0; n0 < Nn; n0 += 64) {
    __syncthreads();
    // stage K tile (row-major) and V tile (transposed)
    #pragma unroll
    for (int i = 0; i < 2; i++) {
      int c = i * 256 + tid;
      int nr = c >> 3;
      int doff = (c & 7) * 8;
      size_t src = (size_t)((n0 + nr) * Bb + b_) * E + h * Dh + doff;
      u16x8 kv = *(const u16x8*)(Kp + src);
      *(u16x8*)(Ks + nr * LDK + doff) = kv;
      u16x8 vv = *(const u16x8*)(Vp + src);
      #pragma unroll
      for (int j = 0; j < 8; j++) Vt[(doff + j) * LDK + nr] = vv[j];
    }
    __syncthreads();

    // S = Q K^T * scale
    f32x4 S[2][4];
    #pragma unroll
    for (int mi = 0; mi < 2; mi++)
      #pragma unroll
      for (int ni = 0; ni < 4; ni++) {
        f32x4 s = {};
        #pragma unroll
        for (int kk = 0; kk < 2; kk++) {
          bf16x8 kf = *(const bf16x8*)(Ks + (ni * 16 + lo) * LDK + kk * 32 + hi * 8);
          s = __builtin_amdgcn_mfma_f32_16x16x32_bf16(q[mi][kk], kf, s, 0, 0, 0);
        }
        S[mi][ni] = s * SCALE;
      }

    // online softmax (row stats via 16-lane shfl reduce), P -> per-wave LDS
    #pragma unroll
    for (int mi = 0; mi < 2; mi++) {
      float alpha[4];
      #pragma unroll
      for (int r = 0; r < 4; r++) {
        float tm = fmaxf(fmaxf(S[mi][0][r], S[mi][1][r]),
                         fmaxf(S[mi][2][r], S[mi][3][r]));
        #pragma unroll
        for (int msk = 1; msk < 16; msk <<= 1) tm = fmaxf(tm, __shfl_xor(tm, msk));
        float mn = fmaxf(mrun[mi][r], tm);
        alpha[r] = __expf(mrun[mi][r] - mn);
        mrun[mi][r] = mn;
        float rs = 0.f;
        #pragma unroll
        for (int ni = 0; ni < 4; ni++) {
          float p = __expf(S[mi][ni][r] - mn);
          S[mi][ni][r] = p;
          rs += p;
        }
        #pragma unroll
        for (int msk = 1; msk < 16; msk <<= 1) rs += __shfl_xor(rs, msk);
        lrun[mi][r] = lrun[mi][r] * alpha[r] + rs;
      }
      #pragma unroll
      for (int df = 0; df < 4; df++)
        #pragma unroll
        for (int r = 0; r < 4; r++) acc[mi][df][r] *= alpha[r];
      #pragma unroll
      for (int ni = 0; ni < 4; ni++)
        #pragma unroll
        for (int r = 0; r < 4; r++)
          Ps[w][(mi * 16 + hi * 4 + r) * LDK + ni * 16 + lo] = f2bf(S[mi][ni][r]);
    }

    // O += P V
    #pragma unroll
    for (int mi = 0; mi < 2; mi++)
      #pragma unroll
      for (int kk = 0; kk < 2; kk++) {
        bf16x8 pf = *(const bf16x8*)(Ps[w] + (mi * 16 + lo) * LDK + kk * 32 + hi * 8);
        #pragma unroll
        for (int df = 0; df < 4; df++) {
          bf16x8 vf = *(const bf16x8*)(Vt + (df * 16 + lo) * LDK + kk * 32 + hi * 8);
          acc[mi][df] = __builtin_amdgcn_mfma_f32_16x16x32_bf16(pf, vf, acc[mi][df], 0, 0, 0);
        }
      }
  }

  #pragma unroll
  for (int mi = 0; mi < 2; mi++)
    #pragma unroll
    for (int df = 0; df < 4; df++)
      #pragma unroll
      for (int r = 0; r < 4; r++) {
        int m = mbase + mi * 16 + hi * 4 + r;
        float o = acc[mi][df][r] / lrun[mi][r];
        O[(size_t)(m * Bb + b_) * E + h * Dh + df * 16 + lo] = f2bf(o);
      }
}

extern "C" void kernel_launch(void* const* d_in, const int* in_sizes, int n_in,
                              void* d_out, int out_size, void* d_ws, size_t ws_size,
                              hipStream_t stream) {
  const float* query = (const float*)d_in[0];
  const float* key   = (const float*)d_in[1];
  const float* value = (const float*)d_in[2];
  const float* Wq = (const float*)d_in[3];
  const float* bq = (const float*)d_in[4];
  const float* Wk = (const float*)d_in[5];
  const float* bk = (const float*)d_in[6];
  const float* Wv = (const float*)d_in[7];
  const float* bv = (const float*)d_in[8];
  const float* Wo = (const float*)d_in[9];
  const float* bo = (const float*)d_in[10];
  float* out = (float*)d_out;

  const size_t XE = (size_t)2048 * 4 * 1024;  // 8,388,608 elements (M*B*E)
  const size_t WE = (size_t)1024 * 1024;
  u16* ws  = (u16*)d_ws;
  u16* Xbuf = ws;            // staging for converted inputs; reused for attn output
  u16* Wqt = ws + XE;
  u16* Wkt = Wqt + WE;
  u16* Wvt = Wkt + WE;
  u16* Wot = Wvt + WE;
  u16* Qp  = Wot + WE;
  u16* Kp  = Qp + XE;
  u16* Vp  = Kp + XE;
  // total: 4*XE + 4*WE u16 = ~75.5 MB of d_ws

  dim3 blk(256);
  dim3 gw(32, 32);
  transpose_cvt<<<gw, blk, 0, stream>>>(Wq, Wqt);
  transpose_cvt<<<gw, blk, 0, stream>>>(Wk, Wkt);
  transpose_cvt<<<gw, blk, 0, stream>>>(Wv, Wvt);
  transpose_cvt<<<gw, blk, 0, stream>>>(Wo, Wot);

  dim3 gg(64, 8);
  int nblk = (int)(XE / 4 / 256);
  cvt_bf16<<<nblk, blk, 0, stream>>>(query, Xbuf, (int)XE);
  gemm_bt_bias<u16><<<gg, blk, 0, stream>>>(Xbuf, Wqt, bq, Qp, 8192, 1024, 1024);
  cvt_bf16<<<nblk, blk, 0, stream>>>(key, Xbuf, (int)XE);
  gemm_bt_bias<u16><<<gg, blk, 0, stream>>>(Xbuf, Wkt, bk, Kp, 8192, 1024, 1024);
  cvt_bf16<<<nblk, blk, 0, stream>>>(value, Xbuf, (int)XE);
  gemm_bt_bias<u16><<<gg, blk, 0, stream>>>(Xbuf, Wvt, bv, Vp, 8192, 1024, 1024);

  dim3 ga(16, 64);
  attn_kernel<<<ga, blk, 0, stream>>>(Qp, Kp, Vp, Xbuf);
  gemm_bt_bias<float><<<gg, blk, 0, stream>>>(Xbuf, Wot, bo, out, 8192, 1024, 1024);
}

// Round 2
// 308.227 us; speedup vs baseline: 1.6754x; 1.6754x over previous
//
#include <hip/hip_runtime.h>

typedef unsigned short u16;
typedef __bf16 bf16x8 __attribute__((ext_vector_type(8)));
typedef float f32x4 __attribute__((ext_vector_type(4)));
typedef unsigned short u16x8 __attribute__((ext_vector_type(8)));
typedef unsigned short u16x4 __attribute__((ext_vector_type(4)));

__device__ __forceinline__ u16 f2bf(float x) {
  union { float f; unsigned int u; } v; v.f = x;
  unsigned int r = v.u + 0x7FFFu + ((v.u >> 16) & 1u);
  return (u16)(r >> 16);
}

__device__ __forceinline__ void gload_lds16(const void* g, void* l) {
  __builtin_amdgcn_global_load_lds(
      (__attribute__((address_space(1))) void*)(g),
      (__attribute__((address_space(3))) void*)(l), 16, 0, 0);
}

// XOR bank swizzle for [rows][64 u16] LDS tiles, 16B-chunk granularity.
// phys_chunk = (col>>3) ^ ((row ^ (row>>3)) & 7). Keeps 16B alignment.
__device__ __forceinline__ int swz_off(int row, int col) {
  return row * 64 + ((((col >> 3) ^ (row ^ (row >> 3))) & 7) << 3) + (col & 7);
}

// ---------------- fp32 -> bf16 elementwise ----------------
__global__ __launch_bounds__(256) void cvt_bf16(const float* __restrict__ in,
                                                u16* __restrict__ out, int n) {
  int i = (blockIdx.x * 256 + threadIdx.x) * 4;
  if (i + 3 < n) {
    float4 v = *(const float4*)(in + i);
    ushort4 o;
    o.x = f2bf(v.x); o.y = f2bf(v.y); o.z = f2bf(v.z); o.w = f2bf(v.w);
    *(ushort4*)(out + i) = o;
  }
}

// ---------------- W (K x N) -> W^T (N x K) bf16 ----------------
__global__ __launch_bounds__(256) void transpose_cvt(const float* __restrict__ W,
                                                     u16* __restrict__ Wt) {
  const int E = 1024;
  __shared__ float tile[32][33];
  int tx = threadIdx.x & 31, ty = threadIdx.x >> 5;  // 32 x 8
  int bx = blockIdx.x * 32, by = blockIdx.y * 32;
  #pragma unroll
  for (int i = 0; i < 32; i += 8)
    tile[ty + i][tx] = W[(size_t)(by + ty + i) * E + bx + tx];
  __syncthreads();
  #pragma unroll
  for (int i = 0; i < 32; i += 8)
    Wt[(size_t)(bx + ty + i) * E + by + tx] = f2bf(tile[tx][ty + i]);
}

// ---------------- C = A @ Bt^T + bias (m97 structure) ----------------
template <typename OutT>
__global__ __launch_bounds__(256) void gemm_bt_bias(
    const u16* __restrict__ A, const u16* __restrict__ Bt,
    const float* __restrict__ bias, OutT* __restrict__ C,
    int R, int K, int N)
{
  __shared__ u16 As[128 * 64];
  __shared__ u16 Bs[128 * 64];
  const int tid = threadIdx.x;
  const int w = tid >> 6;
  const int lane = tid & 63;
  const int lo = lane & 15, hi = lane >> 4;
  const int brow = blockIdx.x * 128;
  const int bcol = blockIdx.y * 128;
  const int wr = (w >> 1) * 64;
  const int wc = (w & 1) * 64;

  f32x4 acc[4][4] = {};

  for (int k0 = 0; k0 < K; k0 += 64) {
    __syncthreads();
    #pragma unroll
    for (int i = 0; i < 4; i++) {
      int c = i * 256 + tid;
      int rowo = c >> 3;
      int ko = (c & 7) * 8;
      gload_lds16(A + (size_t)(brow + rowo) * K + k0 + ko,
                  (void*)(As + (size_t)(i * 256 + w * 64) * 8));
      gload_lds16(Bt + (size_t)(bcol + rowo) * K + k0 + ko,
                  (void*)(Bs + (size_t)(i * 256 + w * 64) * 8));
    }
    __syncthreads();
    #pragma unroll
    for (int kk = 0; kk < 2; kk++) {
      bf16x8 af[4], bfr[4];
      #pragma unroll
      for (int mi = 0; mi < 4; mi++)
        af[mi] = *(const bf16x8*)(As + (wr + mi * 16 + lo) * 64 + kk * 32 + hi * 8);
      #pragma unroll
      for (int ni = 0; ni < 4; ni++)
        bfr[ni] = *(const bf16x8*)(Bs + (wc + ni * 16 + lo) * 64 + kk * 32 + hi * 8);
      #pragma unroll
      for (int mi = 0; mi < 4; mi++)
        #pragma unroll
        for (int ni = 0; ni < 4; ni++)
          acc[mi][ni] = __builtin_amdgcn_mfma_f32_16x16x32_bf16(
              af[mi], bfr[ni], acc[mi][ni], 0, 0, 0);
    }
  }

  #pragma unroll
  for (int mi = 0; mi < 4; mi++)
    #pragma unroll
    for (int ni = 0; ni < 4; ni++) {
      int row = brow + wr + mi * 16 + hi * 4;
      int col = bcol + wc + ni * 16 + lo;
      float bv = bias[col];
      #pragma unroll
      for (int r = 0; r < 4; r++) {
        float v = acc[mi][ni][r] + bv;
        if constexpr (sizeof(OutT) == 2)
          C[(size_t)(row + r) * N + col] = (OutT)f2bf(v);
        else
          C[(size_t)(row + r) * N + col] = (OutT)v;
      }
    }
}

// ---------------- flash attention, swapped-operand (S^T) form ----------------
// Per block: 128 Q rows of one (b,h); 4 waves x 32 rows; KV tiles of 64.
// S^T = mfma(K,Q): lane holds 16 S-values for ONE query row -> lane-local
// softmax (+2 shfl). O^T = mfma(V^T, P): per-lane scalar rescale.
__global__ __launch_bounds__(256) void attn_kernel(
    const u16* __restrict__ Qp, const u16* __restrict__ Kp,
    const u16* __restrict__ Vp, u16* __restrict__ O)
{
  constexpr int Bb = 4, E = 1024, Nn = 2048, Dh = 64;
  constexpr float SCALE = 0.125f;
  __shared__ u16 Ks[64 * 64];      // K tile [n][d], swizzled
  __shared__ u16 Vt[64 * 64];      // V^T tile [d][n], swizzled
  __shared__ u16 Ps[4][32 * 64];   // per-wave P tile [m][n], swizzled

  const int tid = threadIdx.x;
  const int lane = tid & 63;
  const int w = tid >> 6;
  const int lo = lane & 15, hi = lane >> 4;

  // XCD-grouping swizzle: blocks sharing (b,h) (same K/V) -> same XCD L2
  const int wg = blockIdx.x;                  // 0..1023
  const int swz = (wg & 7) * 128 + (wg >> 3); // bijective
  const int b_ = swz >> 8;
  const int h = (swz >> 4) & 15;
  const int mbase = (swz & 15) * 128 + w * 32;

  // Q fragments (B-operand: lane lo = query row, hi = d-chunk)
  bf16x8 q[2][2];
  #pragma unroll
  for (int mi = 0; mi < 2; mi++)
    #pragma unroll
    for (int kk = 0; kk < 2; kk++) {
      int m = mbase + mi * 16 + lo;
      q[mi][kk] = *(const bf16x8*)(Qp + (size_t)(m * Bb + b_) * E + h * Dh + kk * 32 + hi * 8);
    }

  f32x4 acc[2][4] = {};            // O^T: acc[mi][df][r] = O[d=df*16+hi*4+r][m]
  float mrun[2] = {-1e30f, -1e30f};
  float lrun[2] = {0.f, 0.f};

  // prefetch tile 0 into registers (T14: hide HBM latency under compute)
  u16x8 kreg[2], vreg[2];
  #pragma unroll
  for (int i = 0; i < 2; i++) {
    int c = i * 256 + tid;
    int nr = c >> 3;
    int q8 = (c & 7) * 8;
    size_t src = (size_t)(nr * Bb + b_) * E + h * Dh + q8;
    kreg[i] = *(const u16x8*)(Kp + src);
    vreg[i] = *(const u16x8*)(Vp + src);
  }

  for (int n0 = 0; n0 < Nn; n0 += 64) {
    __syncthreads();
    // write staged tile to LDS (K vectorized; V transposed, swizzle spreads banks)
    #pragma unroll
    for (int i = 0; i < 2; i++) {
      int c = i * 256 + tid;
      int nr = c >> 3;
      int q8 = (c & 7) * 8;
      *(u16x8*)(Ks + swz_off(nr, q8)) = kreg[i];
      #pragma unroll
      for (int j = 0; j < 8; j++) Vt[swz_off(q8 + j, nr)] = vreg[i][j];
    }
    __syncthreads();
    // issue next tile's global loads (overlap with compute below)
    if (n0 + 64 < Nn) {
      #pragma unroll
      for (int i = 0; i < 2; i++) {
        int c = i * 256 + tid;
        int nr = c >> 3;
        int q8 = (c & 7) * 8;
        size_t src = (size_t)((n0 + 64 + nr) * Bb + b_) * E + h * Dh + q8;
        kreg[i] = *(const u16x8*)(Kp + src);
        vreg[i] = *(const u16x8*)(Vp + src);
      }
    }

    // S^T = K Q^T * scale : s[mi][ni][r] = S[n=ni*16+hi*4+r][m=mi*16+lo]
    f32x4 s[2][4];
    #pragma unroll
    for (int ni = 0; ni < 4; ni++) {
      bf16x8 kf0 = *(const bf16x8*)(Ks + swz_off(ni * 16 + lo, hi * 8));
      bf16x8 kf1 = *(const bf16x8*)(Ks + swz_off(ni * 16 + lo, 32 + hi * 8));
      #pragma unroll
      for (int mi = 0; mi < 2; mi++) {
        f32x4 t = {};
        t = __builtin_amdgcn_mfma_f32_16x16x32_bf16(kf0, q[mi][0], t, 0, 0, 0);
        t = __builtin_amdgcn_mfma_f32_16x16x32_bf16(kf1, q[mi][1], t, 0, 0, 0);
        s[mi][ni] = t * SCALE;
      }
    }

    // lane-local online softmax (each lane owns one q-row per mi)
    #pragma unroll
    for (int mi = 0; mi < 2; mi++) {
      float tm = -1e30f;
      #pragma unroll
      for (int ni = 0; ni < 4; ni++)
        #pragma unroll
        for (int r = 0; r < 4; r++) tm = fmaxf(tm, s[mi][ni][r]);
      tm = fmaxf(tm, __shfl_xor(tm, 16));
      tm = fmaxf(tm, __shfl_xor(tm, 32));
      float mn = fmaxf(mrun[mi], tm);
      float alpha = __expf(mrun[mi] - mn);
      mrun[mi] = mn;
      float rs = 0.f;
      #pragma unroll
      for (int ni = 0; ni < 4; ni++)
        #pragma unroll
        for (int r = 0; r < 4; r++) {
          float p = __expf(s[mi][ni][r] - mn);
          s[mi][ni][r] = p;
          rs += p;
        }
      rs += __shfl_xor(rs, 16);
      rs += __shfl_xor(rs, 32);
      lrun[mi] = lrun[mi] * alpha + rs;
      #pragma unroll
      for (int df = 0; df < 4; df++) acc[mi][df] *= alpha;
      // P write: 4 x b64 per mi (vs 16 scalar b16 before)
      #pragma unroll
      for (int ni = 0; ni < 4; ni++) {
        u16x4 pk;
        #pragma unroll
        for (int r = 0; r < 4; r++) pk[r] = f2bf(s[mi][ni][r]);
        *(u16x4*)(Ps[w] + swz_off(mi * 16 + lo, ni * 16 + hi * 4)) = pk;
      }
    }

    // O^T += V^T P : acc[mi][df] = mfma(Vt-frag, P-frag)
    #pragma unroll
    for (int kk = 0; kk < 2; kk++) {
      bf16x8 pf[2];
      #pragma unroll
      for (int mi = 0; mi < 2; mi++)
        pf[mi] = *(const bf16x8*)(Ps[w] + swz_off(mi * 16 + lo, kk * 32 + hi * 8));
      #pragma unroll
      for (int df = 0; df < 4; df++) {
        bf16x8 vf = *(const bf16x8*)(Vt + swz_off(df * 16 + lo, kk * 32 + hi * 8));
        #pragma unroll
        for (int mi = 0; mi < 2; mi++)
          acc[mi][df] = __builtin_amdgcn_mfma_f32_16x16x32_bf16(vf, pf[mi], acc[mi][df], 0, 0, 0);
      }
    }
  }

  // epilogue: per-lane scalar 1/l, packed b64 stores
  #pragma unroll
  for (int mi = 0; mi < 2; mi++) {
    float inv = 1.f / lrun[mi];
    int m = mbase + mi * 16 + lo;
    #pragma unroll
    for (int df = 0; df < 4; df++) {
      u16x4 o;
      #pragma unroll
      for (int r = 0; r < 4; r++) o[r] = f2bf(acc[mi][df][r] * inv);
      *(u16x4*)(O + (size_t)(m * Bb + b_) * E + h * Dh + df * 16 + hi * 4) = o;
    }
  }
}

extern "C" void kernel_launch(void* const* d_in, const int* in_sizes, int n_in,
                              void* d_out, int out_size, void* d_ws, size_t ws_size,
                              hipStream_t stream) {
  const float* query = (const float*)d_in[0];
  const float* key   = (const float*)d_in[1];
  const float* value = (const float*)d_in[2];
  const float* Wq = (const float*)d_in[3];
  const float* bq = (const float*)d_in[4];
  const float* Wk = (const float*)d_in[5];
  const float* bk = (const float*)d_in[6];
  const float* Wv = (const float*)d_in[7];
  const float* bv = (const float*)d_in[8];
  const float* Wo = (const float*)d_in[9];
  const float* bo = (const float*)d_in[10];
  float* out = (float*)d_out;

  const size_t XE = (size_t)2048 * 4 * 1024;  // M*B*E
  const size_t WE = (size_t)1024 * 1024;
  u16* ws  = (u16*)d_ws;
  u16* Xbuf = ws;
  u16* Wqt = ws + XE;
  u16* Wkt = Wqt + WE;
  u16* Wvt = Wkt + WE;
  u16* Wot = Wvt + WE;
  u16* Qp  = Wot + WE;
  u16* Kp  = Qp + XE;
  u16* Vp  = Kp + XE;

  dim3 blk(256);
  dim3 gw(32, 32);
  transpose_cvt<<<gw, blk, 0, stream>>>(Wq, Wqt);
  transpose_cvt<<<gw, blk, 0, stream>>>(Wk, Wkt);
  transpose_cvt<<<gw, blk, 0, stream>>>(Wv, Wvt);
  transpose_cvt<<<gw, blk, 0, stream>>>(Wo, Wot);

  dim3 gg(64, 8);
  int nblk = (int)(XE / 4 / 256);
  cvt_bf16<<<nblk, blk, 0, stream>>>(query, Xbuf, (int)XE);
  gemm_bt_bias<u16><<<gg, blk, 0, stream>>>(Xbuf, Wqt, bq, Qp, 8192, 1024, 1024);
  cvt_bf16<<<nblk, blk, 0, stream>>>(key, Xbuf, (int)XE);
  gemm_bt_bias<u16><<<gg, blk, 0, stream>>>(Xbuf, Wkt, bk, Kp, 8192, 1024, 1024);
  cvt_bf16<<<nblk, blk, 0, stream>>>(value, Xbuf, (int)XE);
  gemm_bt_bias<u16><<<gg, blk, 0, stream>>>(Xbuf, Wvt, bv, Vp, 8192, 1024, 1024);

  attn_kernel<<<1024, blk, 0, stream>>>(Qp, Kp, Vp, Xbuf);
  gemm_bt_bias<float><<<gg, blk, 0, stream>>>(Xbuf, Wot, bo, out, 8192, 1024, 1024);
}

// Round 3
// 280.218 us; speedup vs baseline: 1.8429x; 1.1000x over previous
//
#include <hip/hip_runtime.h>

typedef unsigned short u16;
typedef __bf16 bf16x8 __attribute__((ext_vector_type(8)));
typedef float f32x4 __attribute__((ext_vector_type(4)));
typedef unsigned short u16x8 __attribute__((ext_vector_type(8)));
typedef unsigned short u16x4 __attribute__((ext_vector_type(4)));

#define LOG2E 1.44269504088896f

__device__ __forceinline__ float fast_exp2(float x) {
#if __has_builtin(__builtin_amdgcn_exp2f)
  return __builtin_amdgcn_exp2f(x);
#else
  return exp2f(x);
#endif
}

// HW bf16 convert (v_cvt_pk_bf16_f32 path; m240: cast form is fastest)
__device__ __forceinline__ u16 f2bf(float x) {
  union { __bf16 b; u16 u; } c;
  c.b = (__bf16)x;
  return c.u;
}

__device__ __forceinline__ void gload_lds16(const void* g, void* l) {
  __builtin_amdgcn_global_load_lds(
      (__attribute__((address_space(1))) void*)(g),
      (__attribute__((address_space(3))) void*)(l), 16, 0, 0);
}

// XOR bank swizzle for [rows][64 u16] LDS tiles, 16B-chunk granularity.
__device__ __forceinline__ int swz_off(int row, int col) {
  return row * 64 + ((((col >> 3) ^ (row ^ (row >> 3))) & 7) << 3) + (col & 7);
}

// ---------------- fp32 -> bf16 elementwise ----------------
__global__ __launch_bounds__(256) void cvt_bf16(const float* __restrict__ in,
                                                u16* __restrict__ out, int n) {
  int i = (blockIdx.x * 256 + threadIdx.x) * 4;
  if (i + 3 < n) {
    float4 v = *(const float4*)(in + i);
    ushort4 o;
    o.x = f2bf(v.x); o.y = f2bf(v.y); o.z = f2bf(v.z); o.w = f2bf(v.w);
    *(ushort4*)(out + i) = o;
  }
}

// ---------------- W (K x N) -> W^T (N x K) bf16 ----------------
__global__ __launch_bounds__(256) void transpose_cvt(const float* __restrict__ W,
                                                     u16* __restrict__ Wt) {
  const int E = 1024;
  __shared__ float tile[32][33];
  int tx = threadIdx.x & 31, ty = threadIdx.x >> 5;  // 32 x 8
  int bx = blockIdx.x * 32, by = blockIdx.y * 32;
  #pragma unroll
  for (int i = 0; i < 32; i += 8)
    tile[ty + i][tx] = W[(size_t)(by + ty + i) * E + bx + tx];
  __syncthreads();
  #pragma unroll
  for (int i = 0; i < 32; i += 8)
    Wt[(size_t)(bx + ty + i) * E + by + tx] = f2bf(tile[tx][ty + i]);
}

// ---------------- C = (A @ Bt^T + bias) * oscale (m97 structure) ----------------
template <typename OutT>
__global__ __launch_bounds__(256) void gemm_bt_bias(
    const u16* __restrict__ A, const u16* __restrict__ Bt,
    const float* __restrict__ bias, OutT* __restrict__ C,
    int R, int K, int N, float oscale)
{
  __shared__ u16 As[128 * 64];
  __shared__ u16 Bs[128 * 64];
  const int tid = threadIdx.x;
  const int w = tid >> 6;
  const int lane = tid & 63;
  const int lo = lane & 15, hi = lane >> 4;
  const int brow = blockIdx.x * 128;
  const int bcol = blockIdx.y * 128;
  const int wr = (w >> 1) * 64;
  const int wc = (w & 1) * 64;

  f32x4 acc[4][4] = {};

  for (int k0 = 0; k0 < K; k0 += 64) {
    __syncthreads();
    #pragma unroll
    for (int i = 0; i < 4; i++) {
      int c = i * 256 + tid;
      int rowo = c >> 3;
      int ko = (c & 7) * 8;
      gload_lds16(A + (size_t)(brow + rowo) * K + k0 + ko,
                  (void*)(As + (size_t)(i * 256 + w * 64) * 8));
      gload_lds16(Bt + (size_t)(bcol + rowo) * K + k0 + ko,
                  (void*)(Bs + (size_t)(i * 256 + w * 64) * 8));
    }
    __syncthreads();
    #pragma unroll
    for (int kk = 0; kk < 2; kk++) {
      bf16x8 af[4], bfr[4];
      #pragma unroll
      for (int mi = 0; mi < 4; mi++)
        af[mi] = *(const bf16x8*)(As + (wr + mi * 16 + lo) * 64 + kk * 32 + hi * 8);
      #pragma unroll
      for (int ni = 0; ni < 4; ni++)
        bfr[ni] = *(const bf16x8*)(Bs + (wc + ni * 16 + lo) * 64 + kk * 32 + hi * 8);
      #pragma unroll
      for (int mi = 0; mi < 4; mi++)
        #pragma unroll
        for (int ni = 0; ni < 4; ni++)
          acc[mi][ni] = __builtin_amdgcn_mfma_f32_16x16x32_bf16(
              af[mi], bfr[ni], acc[mi][ni], 0, 0, 0);
    }
  }

  #pragma unroll
  for (int mi = 0; mi < 4; mi++)
    #pragma unroll
    for (int ni = 0; ni < 4; ni++) {
      int row = brow + wr + mi * 16 + hi * 4;
      int col = bcol + wc + ni * 16 + lo;
      float bv = bias[col];
      #pragma unroll
      for (int r = 0; r < 4; r++) {
        float v = (acc[mi][ni][r] + bv) * oscale;
        if constexpr (sizeof(OutT) == 2)
          C[(size_t)(row + r) * N + col] = (OutT)f2bf(v);
        else
          C[(size_t)(row + r) * N + col] = (OutT)v;
      }
    }
}

// ---------------- flash attention, swapped-operand (S^T), exp2 domain ---------
// Q pre-scaled by SCALE*log2(e) in the projection. Per block: 128 Q rows of one
// (b,h); 4 waves x 32 rows; KV tiles of 64. Lane-local online softmax with
// defer-max (T13). V transposed via 4x4 register blocks (vector DS writes).
__global__ __launch_bounds__(256) void attn_kernel(
    const u16* __restrict__ Qp, const u16* __restrict__ Kp,
    const u16* __restrict__ Vp, u16* __restrict__ O)
{
  constexpr int Bb = 4, E = 1024, Nn = 2048, Dh = 64;
  constexpr float THR = 8.0f;     // defer-max threshold (log2 units)
  __shared__ u16 Ks[64 * 64];      // K tile [n][d], swizzled
  __shared__ u16 Vt[64 * 64];      // V^T tile [d][n], swizzled
  __shared__ u16 Ps[4][32 * 64];   // per-wave P tile [m][n], swizzled

  const int tid = threadIdx.x;
  const int lane = tid & 63;
  const int w = tid >> 6;
  const int lo = lane & 15, hi = lane >> 4;

  // XCD-grouping swizzle: blocks sharing (b,h) -> same XCD L2
  const int wg = blockIdx.x;
  const int swz = (wg & 7) * 128 + (wg >> 3);
  const int b_ = swz >> 8;
  const int h = (swz >> 4) & 15;
  const int mbase = (swz & 15) * 128 + w * 32;

  // Q fragments (pre-scaled); lane lo = query row, hi = d-chunk
  bf16x8 q[2][2];
  #pragma unroll
  for (int mi = 0; mi < 2; mi++)
    #pragma unroll
    for (int kk = 0; kk < 2; kk++) {
      int m = mbase + mi * 16 + lo;
      q[mi][kk] = *(const bf16x8*)(Qp + (size_t)(m * Bb + b_) * E + h * Dh + kk * 32 + hi * 8);
    }

  f32x4 acc[2][4] = {};
  float mrun[2] = {-3e38f, -3e38f};
  float lrun[2] = {0.f, 0.f};

  // staging assignments
  const int nrK = tid >> 3;            // + i*32
  const int q8K = (tid & 7) * 8;
  const int dq = (tid & 15) * 4;       // V: 4x4 block at (nq.., dq..)
  const int nq = (tid >> 4) * 4;

  // prefetch tile 0
  u16x8 kreg[2];
  u16x4 vreg[4];
  #pragma unroll
  for (int i = 0; i < 2; i++)
    kreg[i] = *(const u16x8*)(Kp + (size_t)((i * 32 + nrK) * Bb + b_) * E + h * Dh + q8K);
  #pragma unroll
  for (int j = 0; j < 4; j++)
    vreg[j] = *(const u16x4*)(Vp + (size_t)((nq + j) * Bb + b_) * E + h * Dh + dq);

  for (int n0 = 0; n0 < Nn; n0 += 64) {
    __syncthreads();
    // stage K (vector rows) and V^T (4x4 register-transposed blocks)
    #pragma unroll
    for (int i = 0; i < 2; i++)
      *(u16x8*)(Ks + swz_off(i * 32 + nrK, q8K)) = kreg[i];
    #pragma unroll
    for (int jw = 0; jw < 4; jw++) {
      u16x4 colv;
      #pragma unroll
      for (int j = 0; j < 4; j++) colv[j] = vreg[j][jw];
      *(u16x4*)(Vt + swz_off(dq + jw, nq)) = colv;
    }
    __syncthreads();
    // issue next tile's global loads (hide HBM under compute)
    if (n0 + 64 < Nn) {
      #pragma unroll
      for (int i = 0; i < 2; i++)
        kreg[i] = *(const u16x8*)(Kp + (size_t)((n0 + 64 + i * 32 + nrK) * Bb + b_) * E + h * Dh + q8K);
      #pragma unroll
      for (int j = 0; j < 4; j++)
        vreg[j] = *(const u16x4*)(Vp + (size_t)((n0 + 64 + nq + j) * Bb + b_) * E + h * Dh + dq);
    }

    // S^T = K Q^T (already in log2 domain): s[mi][ni][r] = S[n][m=mi*16+lo]
    f32x4 s[2][4];
    __builtin_amdgcn_s_setprio(1);
    #pragma unroll
    for (int ni = 0; ni < 4; ni++) {
      bf16x8 kf0 = *(const bf16x8*)(Ks + swz_off(ni * 16 + lo, hi * 8));
      bf16x8 kf1 = *(const bf16x8*)(Ks + swz_off(ni * 16 + lo, 32 + hi * 8));
      #pragma unroll
      for (int mi = 0; mi < 2; mi++) {
        f32x4 t = {};
        t = __builtin_amdgcn_mfma_f32_16x16x32_bf16(kf0, q[mi][0], t, 0, 0, 0);
        t = __builtin_amdgcn_mfma_f32_16x16x32_bf16(kf1, q[mi][1], t, 0, 0, 0);
        s[mi][ni] = t;
      }
    }
    __builtin_amdgcn_s_setprio(0);

    // lane-local online softmax with defer-max
    #pragma unroll
    for (int mi = 0; mi < 2; mi++) {
      float tm = -3e38f;
      #pragma unroll
      for (int ni = 0; ni < 4; ni++)
        #pragma unroll
        for (int r = 0; r < 4; r++) tm = fmaxf(tm, s[mi][ni][r]);
      tm = fmaxf(tm, __shfl_xor(tm, 16));
      tm = fmaxf(tm, __shfl_xor(tm, 32));
      if (!__all(tm <= mrun[mi] + THR)) {
        float mn = fmaxf(mrun[mi], tm);
        float al = fast_exp2(mrun[mi] - mn);
        mrun[mi] = mn;
        lrun[mi] *= al;
        #pragma unroll
        for (int df = 0; df < 4; df++) acc[mi][df] *= al;
      }
      const float m_ = mrun[mi];
      float rs = 0.f;
      #pragma unroll
      for (int ni = 0; ni < 4; ni++)
        #pragma unroll
        for (int r = 0; r < 4; r++) {
          float p = fast_exp2(s[mi][ni][r] - m_);
          s[mi][ni][r] = p;
          rs += p;
        }
      rs += __shfl_xor(rs, 16);
      rs += __shfl_xor(rs, 32);
      lrun[mi] += rs;
      #pragma unroll
      for (int ni = 0; ni < 4; ni++) {
        u16x4 pk;
        #pragma unroll
        for (int r = 0; r < 4; r++) pk[r] = f2bf(s[mi][ni][r]);
        *(u16x4*)(Ps[w] + swz_off(mi * 16 + lo, ni * 16 + hi * 4)) = pk;
      }
    }

    // O^T += V^T P
    __builtin_amdgcn_s_setprio(1);
    #pragma unroll
    for (int kk = 0; kk < 2; kk++) {
      bf16x8 pf[2];
      #pragma unroll
      for (int mi = 0; mi < 2; mi++)
        pf[mi] = *(const bf16x8*)(Ps[w] + swz_off(mi * 16 + lo, kk * 32 + hi * 8));
      #pragma unroll
      for (int df = 0; df < 4; df++) {
        bf16x8 vf = *(const bf16x8*)(Vt + swz_off(df * 16 + lo, kk * 32 + hi * 8));
        #pragma unroll
        for (int mi = 0; mi < 2; mi++)
          acc[mi][df] = __builtin_amdgcn_mfma_f32_16x16x32_bf16(vf, pf[mi], acc[mi][df], 0, 0, 0);
      }
    }
    __builtin_amdgcn_s_setprio(0);
  }

  // epilogue: per-lane scalar 1/l, packed b64 stores
  #pragma unroll
  for (int mi = 0; mi < 2; mi++) {
    float inv = 1.f / lrun[mi];
    int m = mbase + mi * 16 + lo;
    #pragma unroll
    for (int df = 0; df < 4; df++) {
      u16x4 o;
      #pragma unroll
      for (int r = 0; r < 4; r++) o[r] = f2bf(acc[mi][df][r] * inv);
      *(u16x4*)(O + (size_t)(m * Bb + b_) * E + h * Dh + df * 16 + hi * 4) = o;
    }
  }
}

extern "C" void kernel_launch(void* const* d_in, const int* in_sizes, int n_in,
                              void* d_out, int out_size, void* d_ws, size_t ws_size,
                              hipStream_t stream) {
  const float* query = (const float*)d_in[0];
  const float* key   = (const float*)d_in[1];
  const float* value = (const float*)d_in[2];
  const float* Wq = (const float*)d_in[3];
  const float* bq = (const float*)d_in[4];
  const float* Wk = (const float*)d_in[5];
  const float* bk = (const float*)d_in[6];
  const float* Wv = (const float*)d_in[7];
  const float* bv = (const float*)d_in[8];
  const float* Wo = (const float*)d_in[9];
  const float* bo = (const float*)d_in[10];
  float* out = (float*)d_out;

  const float QSCALE = 0.125f * LOG2E;  // 1/sqrt(64) * log2(e)

  const size_t XE = (size_t)2048 * 4 * 1024;  // M*B*E
  const size_t WE = (size_t)1024 * 1024;
  u16* ws  = (u16*)d_ws;
  u16* Xbuf = ws;
  u16* Wqt = ws + XE;
  u16* Wkt = Wqt + WE;
  u16* Wvt = Wkt + WE;
  u16* Wot = Wvt + WE;
  u16* Qp  = Wot + WE;
  u16* Kp  = Qp + XE;
  u16* Vp  = Kp + XE;

  dim3 blk(256);
  dim3 gw(32, 32);
  transpose_cvt<<<gw, blk, 0, stream>>>(Wq, Wqt);
  transpose_cvt<<<gw, blk, 0, stream>>>(Wk, Wkt);
  transpose_cvt<<<gw, blk, 0, stream>>>(Wv, Wvt);
  transpose_cvt<<<gw, blk, 0, stream>>>(Wo, Wot);

  dim3 gg(64, 8);
  int nblk = (int)(XE / 4 / 256);
  cvt_bf16<<<nblk, blk, 0, stream>>>(query, Xbuf, (int)XE);
  gemm_bt_bias<u16><<<gg, blk, 0, stream>>>(Xbuf, Wqt, bq, Qp, 8192, 1024, 1024, QSCALE);
  cvt_bf16<<<nblk, blk, 0, stream>>>(key, Xbuf, (int)XE);
  gemm_bt_bias<u16><<<gg, blk, 0, stream>>>(Xbuf, Wkt, bk, Kp, 8192, 1024, 1024, 1.0f);
  cvt_bf16<<<nblk, blk, 0, stream>>>(value, Xbuf, (int)XE);
  gemm_bt_bias<u16><<<gg, blk, 0, stream>>>(Xbuf, Wvt, bv, Vp, 8192, 1024, 1024, 1.0f);

  attn_kernel<<<1024, blk, 0, stream>>>(Qp, Kp, Vp, Xbuf);
  gemm_bt_bias<float><<<gg, blk, 0, stream>>>(Xbuf, Wot, bo, out, 8192, 1024, 1024, 1.0f);
}

// Round 4
// 242.559 us; speedup vs baseline: 2.1290x; 1.1553x over previous
//
#include <hip/hip_runtime.h>

typedef unsigned short u16;
typedef __bf16 bf16x8 __attribute__((ext_vector_type(8)));
typedef float f32x4 __attribute__((ext_vector_type(4)));
typedef unsigned short u16x8 __attribute__((ext_vector_type(8)));
typedef unsigned short u16x4 __attribute__((ext_vector_type(4)));

#define LOG2E 1.44269504088896f

__device__ __forceinline__ float fast_exp2(float x) {
#if __has_builtin(__builtin_amdgcn_exp2f)
  return __builtin_amdgcn_exp2f(x);
#else
  return exp2f(x);
#endif
}

// HW bf16 convert (compiler emits v_cvt_pk_bf16_f32 pairs)
__device__ __forceinline__ u16 f2bf(float x) {
  union { __bf16 b; u16 u; } c;
  c.b = (__bf16)x;
  return c.u;
}

__device__ __forceinline__ void gload_lds16(const void* g, void* l) {
  __builtin_amdgcn_global_load_lds(
      (__attribute__((address_space(1))) void*)(g),
      (__attribute__((address_space(3))) void*)(l), 16, 0, 0);
}

// XOR bank swizzle for [rows][64 u16] LDS tiles, 16B-chunk granularity.
__device__ __forceinline__ int swz_off(int row, int col) {
  return row * 64 + ((((col >> 3) ^ (row ^ (row >> 3))) & 7) << 3) + (col & 7);
}

// ---------------- all 4 weights: W (K x N) -> W^T (N x K) bf16, one dispatch --
__global__ __launch_bounds__(256) void transpose_cvt4(
    const float* __restrict__ Wq, const float* __restrict__ Wk,
    const float* __restrict__ Wv, const float* __restrict__ Wo,
    u16* __restrict__ Wqt, u16* __restrict__ Wkt,
    u16* __restrict__ Wvt, u16* __restrict__ Wot) {
  const int E = 1024;
  const float* W = blockIdx.z == 0 ? Wq : blockIdx.z == 1 ? Wk
                   : blockIdx.z == 2 ? Wv : Wo;
  u16* Wt = blockIdx.z == 0 ? Wqt : blockIdx.z == 1 ? Wkt
            : blockIdx.z == 2 ? Wvt : Wot;
  __shared__ float tile[32][33];
  int tx = threadIdx.x & 31, ty = threadIdx.x >> 5;  // 32 x 8
  int bx = blockIdx.x * 32, by = blockIdx.y * 32;
  #pragma unroll
  for (int i = 0; i < 32; i += 8)
    tile[ty + i][tx] = W[(size_t)(by + ty + i) * E + bx + tx];
  __syncthreads();
  #pragma unroll
  for (int i = 0; i < 32; i += 8)
    Wt[(size_t)(bx + ty + i) * E + by + tx] = f2bf(tile[tx][ty + i]);
}

// ---------------- fused Q/K/V projection: one dispatch, grid.z selects ------
// A is fp32 (raw query/key/value); conversion fused into reg-staged A path
// with T2 XOR-swizzled LDS writes/reads. B (W^T bf16) via global_load_lds.
__global__ __launch_bounds__(256) void proj_qkv(
    const float* __restrict__ Xq, const float* __restrict__ Xk,
    const float* __restrict__ Xv,
    const u16* __restrict__ Wqt, const u16* __restrict__ Wkt,
    const u16* __restrict__ Wvt,
    const float* __restrict__ bq, const float* __restrict__ bk,
    const float* __restrict__ bv,
    u16* __restrict__ Qp, u16* __restrict__ Kp, u16* __restrict__ Vp,
    float qscale)
{
  constexpr int K = 1024, N = 1024;
  const float* A; const u16* Bt; const float* bias; u16* C; float oscale;
  if (blockIdx.z == 0)      { A = Xq; Bt = Wqt; bias = bq; C = Qp; oscale = qscale; }
  else if (blockIdx.z == 1) { A = Xk; Bt = Wkt; bias = bk; C = Kp; oscale = 1.f; }
  else                      { A = Xv; Bt = Wvt; bias = bv; C = Vp; oscale = 1.f; }

  __shared__ u16 As[128 * 64];   // swizzled
  __shared__ u16 Bs[128 * 64];   // linear (gload_lds dest)
  const int tid = threadIdx.x;
  const int w = tid >> 6;
  const int lane = tid & 63;
  const int lo = lane & 15, hi = lane >> 4;
  const int brow = blockIdx.x * 128;
  const int bcol = blockIdx.y * 128;
  const int wr = (w >> 1) * 64;
  const int wc = (w & 1) * 64;

  f32x4 acc[4][4] = {};

  for (int k0 = 0; k0 < K; k0 += 64) {
    __syncthreads();
    #pragma unroll
    for (int i = 0; i < 4; i++) {
      int c = i * 256 + tid;
      int rowo = c >> 3;
      int ko = (c & 7) * 8;
      gload_lds16(Bt + (size_t)(bcol + rowo) * K + k0 + ko,
                  (void*)(Bs + (size_t)(i * 256 + w * 64) * 8));
    }
    #pragma unroll
    for (int i = 0; i < 4; i++) {
      int c = i * 256 + tid;
      int rowo = c >> 3;
      int ko = (c & 7) * 8;
      const float* Ap = A + (size_t)(brow + rowo) * K + k0 + ko;
      float4 v0 = *(const float4*)Ap;
      float4 v1 = *(const float4*)(Ap + 4);
      u16x8 ab;
      ab[0] = f2bf(v0.x); ab[1] = f2bf(v0.y); ab[2] = f2bf(v0.z); ab[3] = f2bf(v0.w);
      ab[4] = f2bf(v1.x); ab[5] = f2bf(v1.y); ab[6] = f2bf(v1.z); ab[7] = f2bf(v1.w);
      *(u16x8*)(As + swz_off(rowo, ko)) = ab;
    }
    __syncthreads();
    #pragma unroll
    for (int kk = 0; kk < 2; kk++) {
      bf16x8 af[4], bfr[4];
      #pragma unroll
      for (int mi = 0; mi < 4; mi++)
        af[mi] = *(const bf16x8*)(As + swz_off(wr + mi * 16 + lo, kk * 32 + hi * 8));
      #pragma unroll
      for (int ni = 0; ni < 4; ni++)
        bfr[ni] = *(const bf16x8*)(Bs + (wc + ni * 16 + lo) * 64 + kk * 32 + hi * 8);
      #pragma unroll
      for (int mi = 0; mi < 4; mi++)
        #pragma unroll
        for (int ni = 0; ni < 4; ni++)
          acc[mi][ni] = __builtin_amdgcn_mfma_f32_16x16x32_bf16(
              af[mi], bfr[ni], acc[mi][ni], 0, 0, 0);
    }
  }

  #pragma unroll
  for (int mi = 0; mi < 4; mi++)
    #pragma unroll
    for (int ni = 0; ni < 4; ni++) {
      int row = brow + wr + mi * 16 + hi * 4;
      int col = bcol + wc + ni * 16 + lo;
      float bv = bias[col];
      #pragma unroll
      for (int r = 0; r < 4; r++) {
        float v = (acc[mi][ni][r] + bv) * oscale;
        C[(size_t)(row + r) * N + col] = f2bf(v);
      }
    }
}

// ---------------- output projection: C = (A @ Bt^T + bias), fp32 out --------
__global__ __launch_bounds__(256) void gemm_out(
    const u16* __restrict__ A, const u16* __restrict__ Bt,
    const float* __restrict__ bias, float* __restrict__ C)
{
  constexpr int K = 1024, N = 1024;
  __shared__ u16 As[128 * 64];
  __shared__ u16 Bs[128 * 64];
  const int tid = threadIdx.x;
  const int w = tid >> 6;
  const int lane = tid & 63;
  const int lo = lane & 15, hi = lane >> 4;
  const int brow = blockIdx.x * 128;
  const int bcol = blockIdx.y * 128;
  const int wr = (w >> 1) * 64;
  const int wc = (w & 1) * 64;

  f32x4 acc[4][4] = {};

  for (int k0 = 0; k0 < K; k0 += 64) {
    __syncthreads();
    #pragma unroll
    for (int i = 0; i < 4; i++) {
      int c = i * 256 + tid;
      int rowo = c >> 3;
      int ko = (c & 7) * 8;
      gload_lds16(A + (size_t)(brow + rowo) * K + k0 + ko,
                  (void*)(As + (size_t)(i * 256 + w * 64) * 8));
      gload_lds16(Bt + (size_t)(bcol + rowo) * K + k0 + ko,
                  (void*)(Bs + (size_t)(i * 256 + w * 64) * 8));
    }
    __syncthreads();
    #pragma unroll
    for (int kk = 0; kk < 2; kk++) {
      bf16x8 af[4], bfr[4];
      #pragma unroll
      for (int mi = 0; mi < 4; mi++)
        af[mi] = *(const bf16x8*)(As + (wr + mi * 16 + lo) * 64 + kk * 32 + hi * 8);
      #pragma unroll
      for (int ni = 0; ni < 4; ni++)
        bfr[ni] = *(const bf16x8*)(Bs + (wc + ni * 16 + lo) * 64 + kk * 32 + hi * 8);
      #pragma unroll
      for (int mi = 0; mi < 4; mi++)
        #pragma unroll
        for (int ni = 0; ni < 4; ni++)
          acc[mi][ni] = __builtin_amdgcn_mfma_f32_16x16x32_bf16(
              af[mi], bfr[ni], acc[mi][ni], 0, 0, 0);
    }
  }

  #pragma unroll
  for (int mi = 0; mi < 4; mi++)
    #pragma unroll
    for (int ni = 0; ni < 4; ni++) {
      int row = brow + wr + mi * 16 + hi * 4;
      int col = bcol + wc + ni * 16 + lo;
      float bv = bias[col];
      #pragma unroll
      for (int r = 0; r < 4; r++)
        C[(size_t)(row + r) * N + col] = acc[mi][ni][r] + bv;
    }
}

// ---------------- flash attention, swapped-operand, exp2, double-buffered ----
// ONE barrier per KV tile: write buf[it] -> barrier -> issue next loads ->
// compute buf[it]. Buf written at iter i is read at i, overwritten at i+2;
// the barrier at i+1 orders readers(i) before writers(i+2).
__global__ __launch_bounds__(256) void attn_kernel(
    const u16* __restrict__ Qp, const u16* __restrict__ Kp,
    const u16* __restrict__ Vp, u16* __restrict__ O)
{
  constexpr int Bb = 4, E = 1024, Nn = 2048, Dh = 64;
  constexpr float THR = 8.0f;       // defer-max threshold (log2 units)
  __shared__ u16 Ks[2][64 * 64];    // K tile [n][d], swizzled
  __shared__ u16 Vt[2][64 * 64];    // V^T tile [d][n], swizzled
  __shared__ u16 Ps[4][32 * 64];    // per-wave P tile [m][n], swizzled

  const int tid = threadIdx.x;
  const int lane = tid & 63;
  const int w = tid >> 6;
  const int lo = lane & 15, hi = lane >> 4;

  // XCD-grouping swizzle: blocks sharing (b,h) -> same XCD L2
  const int wg = blockIdx.x;
  const int swz = (wg & 7) * 128 + (wg >> 3);
  const int b_ = swz >> 8;
  const int h = (swz >> 4) & 15;
  const int mbase = (swz & 15) * 128 + w * 32;

  // Q fragments (pre-scaled by 1/sqrt(d)*log2e in projection)
  bf16x8 q[2][2];
  #pragma unroll
  for (int mi = 0; mi < 2; mi++)
    #pragma unroll
    for (int kk = 0; kk < 2; kk++) {
      int m = mbase + mi * 16 + lo;
      q[mi][kk] = *(const bf16x8*)(Qp + (size_t)(m * Bb + b_) * E + h * Dh + kk * 32 + hi * 8);
    }

  f32x4 acc[2][4] = {};
  float mrun[2] = {-3e38f, -3e38f};
  float lrun[2] = {0.f, 0.f};

  // staging assignments
  const int nrK = tid >> 3;            // + i*32
  const int q8K = (tid & 7) * 8;
  const int dq = (tid & 15) * 4;       // V: 4x4 block at (nq.., dq..)
  const int nq = (tid >> 4) * 4;

  // prefetch tile 0
  u16x8 kreg[2];
  u16x4 vreg[4];
  #pragma unroll
  for (int i = 0; i < 2; i++)
    kreg[i] = *(const u16x8*)(Kp + (size_t)((i * 32 + nrK) * Bb + b_) * E + h * Dh + q8K);
  #pragma unroll
  for (int j = 0; j < 4; j++)
    vreg[j] = *(const u16x4*)(Vp + (size_t)((nq + j) * Bb + b_) * E + h * Dh + dq);

  int it = 0;
  for (int n0 = 0; n0 < Nn; n0 += 64, it ^= 1) {
    // stage regs -> LDS buf[it]
    #pragma unroll
    for (int i = 0; i < 2; i++)
      *(u16x8*)(&Ks[it][swz_off(i * 32 + nrK, q8K)]) = kreg[i];
    #pragma unroll
    for (int jw = 0; jw < 4; jw++) {
      u16x4 colv;
      #pragma unroll
      for (int j = 0; j < 4; j++) colv[j] = vreg[j][jw];
      *(u16x4*)(&Vt[it][swz_off(dq + jw, nq)]) = colv;
    }
    __syncthreads();
    // issue next tile's global loads AFTER the barrier so the barrier's
    // vmcnt(0) drain doesn't serialize them; they retire under compute.
    if (n0 + 64 < Nn) {
      #pragma unroll
      for (int i = 0; i < 2; i++)
        kreg[i] = *(const u16x8*)(Kp + (size_t)((n0 + 64 + i * 32 + nrK) * Bb + b_) * E + h * Dh + q8K);
      #pragma unroll
      for (int j = 0; j < 4; j++)
        vreg[j] = *(const u16x4*)(Vp + (size_t)((n0 + 64 + nq + j) * Bb + b_) * E + h * Dh + dq);
    }
    const u16* ksp = &Ks[it][0];
    const u16* vtp = &Vt[it][0];

    // S^T = K Q^T (log2 domain): s[mi][ni][r] = S[n][m=mi*16+lo]
    f32x4 s[2][4];
    __builtin_amdgcn_s_setprio(1);
    #pragma unroll
    for (int ni = 0; ni < 4; ni++) {
      bf16x8 kf0 = *(const bf16x8*)(ksp + swz_off(ni * 16 + lo, hi * 8));
      bf16x8 kf1 = *(const bf16x8*)(ksp + swz_off(ni * 16 + lo, 32 + hi * 8));
      #pragma unroll
      for (int mi = 0; mi < 2; mi++) {
        f32x4 t = {};
        t = __builtin_amdgcn_mfma_f32_16x16x32_bf16(kf0, q[mi][0], t, 0, 0, 0);
        t = __builtin_amdgcn_mfma_f32_16x16x32_bf16(kf1, q[mi][1], t, 0, 0, 0);
        s[mi][ni] = t;
      }
    }
    __builtin_amdgcn_s_setprio(0);

    // lane-local online softmax with defer-max
    #pragma unroll
    for (int mi = 0; mi < 2; mi++) {
      float tm = -3e38f;
      #pragma unroll
      for (int ni = 0; ni < 4; ni++)
        #pragma unroll
        for (int r = 0; r < 4; r++) tm = fmaxf(tm, s[mi][ni][r]);
      tm = fmaxf(tm, __shfl_xor(tm, 16));
      tm = fmaxf(tm, __shfl_xor(tm, 32));
      if (!__all(tm <= mrun[mi] + THR)) {
        float mn = fmaxf(mrun[mi], tm);
        float al = fast_exp2(mrun[mi] - mn);
        mrun[mi] = mn;
        lrun[mi] *= al;
        #pragma unroll
        for (int df = 0; df < 4; df++) acc[mi][df] *= al;
      }
      const float m_ = mrun[mi];
      float rs = 0.f;
      #pragma unroll
      for (int ni = 0; ni < 4; ni++)
        #pragma unroll
        for (int r = 0; r < 4; r++) {
          float p = fast_exp2(s[mi][ni][r] - m_);
          s[mi][ni][r] = p;
          rs += p;
        }
      rs += __shfl_xor(rs, 16);
      rs += __shfl_xor(rs, 32);
      lrun[mi] += rs;
      #pragma unroll
      for (int ni = 0; ni < 4; ni++) {
        u16x4 pk;
        #pragma unroll
        for (int r = 0; r < 4; r++) pk[r] = f2bf(s[mi][ni][r]);
        *(u16x4*)(Ps[w] + swz_off(mi * 16 + lo, ni * 16 + hi * 4)) = pk;
      }
    }

    // O^T += V^T P
    __builtin_amdgcn_s_setprio(1);
    #pragma unroll
    for (int kk = 0; kk < 2; kk++) {
      bf16x8 pf[2];
      #pragma unroll
      for (int mi = 0; mi < 2; mi++)
        pf[mi] = *(const bf16x8*)(Ps[w] + swz_off(mi * 16 + lo, kk * 32 + hi * 8));
      #pragma unroll
      for (int df = 0; df < 4; df++) {
        bf16x8 vf = *(const bf16x8*)(vtp + swz_off(df * 16 + lo, kk * 32 + hi * 8));
        #pragma unroll
        for (int mi = 0; mi < 2; mi++)
          acc[mi][df] = __builtin_amdgcn_mfma_f32_16x16x32_bf16(vf, pf[mi], acc[mi][df], 0, 0, 0);
      }
    }
    __builtin_amdgcn_s_setprio(0);
  }

  // epilogue: per-lane scalar 1/l, packed b64 stores
  #pragma unroll
  for (int mi = 0; mi < 2; mi++) {
    float inv = 1.f / lrun[mi];
    int m = mbase + mi * 16 + lo;
    #pragma unroll
    for (int df = 0; df < 4; df++) {
      u16x4 o;
      #pragma unroll
      for (int r = 0; r < 4; r++) o[r] = f2bf(acc[mi][df][r] * inv);
      *(u16x4*)(O + (size_t)(m * Bb + b_) * E + h * Dh + df * 16 + hi * 4) = o;
    }
  }
}

extern "C" void kernel_launch(void* const* d_in, const int* in_sizes, int n_in,
                              void* d_out, int out_size, void* d_ws, size_t ws_size,
                              hipStream_t stream) {
  const float* query = (const float*)d_in[0];
  const float* key   = (const float*)d_in[1];
  const float* value = (const float*)d_in[2];
  const float* Wq = (const float*)d_in[3];
  const float* bq = (const float*)d_in[4];
  const float* Wk = (const float*)d_in[5];
  const float* bk = (const float*)d_in[6];
  const float* Wv = (const float*)d_in[7];
  const float* bv = (const float*)d_in[8];
  const float* Wo = (const float*)d_in[9];
  const float* bo = (const float*)d_in[10];
  float* out = (float*)d_out;

  const float QSCALE = 0.125f * LOG2E;  // 1/sqrt(64) * log2(e)

  const size_t XE = (size_t)2048 * 4 * 1024;  // M*B*E
  const size_t WE = (size_t)1024 * 1024;
  u16* ws  = (u16*)d_ws;
  u16* Qp  = ws;
  u16* Kp  = Qp + XE;
  u16* Vp  = Kp + XE;
  u16* Ob  = Vp + XE;       // attention output (bf16)
  u16* Wqt = Ob + XE;
  u16* Wkt = Wqt + WE;
  u16* Wvt = Wkt + WE;
  u16* Wot = Wvt + WE;
  // total: 4*XE + 4*WE u16 = ~75.5 MB of d_ws

  dim3 blk(256);
  transpose_cvt4<<<dim3(32, 32, 4), blk, 0, stream>>>(
      Wq, Wk, Wv, Wo, Wqt, Wkt, Wvt, Wot);

  proj_qkv<<<dim3(64, 8, 3), blk, 0, stream>>>(
      query, key, value, Wqt, Wkt, Wvt, bq, bk, bv, Qp, Kp, Vp, QSCALE);

  attn_kernel<<<1024, blk, 0, stream>>>(Qp, Kp, Vp, Ob);

  gemm_out<<<dim3(64, 8), blk, 0, stream>>>(Ob, Wot, bo, out);
}

// Round 5
// 236.841 us; speedup vs baseline: 2.1804x; 1.0241x over previous
//
#include <hip/hip_runtime.h>

typedef unsigned short u16;
typedef __bf16 bf16x8 __attribute__((ext_vector_type(8)));
typedef float f32x4 __attribute__((ext_vector_type(4)));
typedef unsigned short u16x8 __attribute__((ext_vector_type(8)));
typedef unsigned short u16x4 __attribute__((ext_vector_type(4)));

#define LOG2E 1.44269504088896f

__device__ __forceinline__ float fast_exp2(float x) {
#if __has_builtin(__builtin_amdgcn_exp2f)
  return __builtin_amdgcn_exp2f(x);
#else
  return exp2f(x);
#endif
}

// HW bf16 convert (compiler emits v_cvt_pk_bf16_f32 pairs)
__device__ __forceinline__ u16 f2bf(float x) {
  union { __bf16 b; u16 u; } c;
  c.b = (__bf16)x;
  return c.u;
}

__device__ __forceinline__ void gload_lds16(const void* g, void* l) {
  __builtin_amdgcn_global_load_lds(
      (__attribute__((address_space(1))) void*)(g),
      (__attribute__((address_space(3))) void*)(l), 16, 0, 0);
}

// XOR bank swizzle for [rows][64 u16] LDS tiles, 16B-chunk granularity.
__device__ __forceinline__ int swz_off(int row, int col) {
  return row * 64 + ((((col >> 3) ^ (row ^ (row >> 3))) & 7) << 3) + (col & 7);
}

// ---------------- all 4 weights: W (K x N) -> W^T (N x K) bf16, one dispatch --
__global__ __launch_bounds__(256) void transpose_cvt4(
    const float* __restrict__ Wq, const float* __restrict__ Wk,
    const float* __restrict__ Wv, const float* __restrict__ Wo,
    u16* __restrict__ Wqt, u16* __restrict__ Wkt,
    u16* __restrict__ Wvt, u16* __restrict__ Wot) {
  const int E = 1024;
  const float* W = blockIdx.z == 0 ? Wq : blockIdx.z == 1 ? Wk
                   : blockIdx.z == 2 ? Wv : Wo;
  u16* Wt = blockIdx.z == 0 ? Wqt : blockIdx.z == 1 ? Wkt
            : blockIdx.z == 2 ? Wvt : Wot;
  __shared__ float tile[32][33];
  int tx = threadIdx.x & 31, ty = threadIdx.x >> 5;  // 32 x 8
  int bx = blockIdx.x * 32, by = blockIdx.y * 32;
  #pragma unroll
  for (int i = 0; i < 32; i += 8)
    tile[ty + i][tx] = W[(size_t)(by + ty + i) * E + bx + tx];
  __syncthreads();
  #pragma unroll
  for (int i = 0; i < 32; i += 8)
    Wt[(size_t)(bx + ty + i) * E + by + tx] = f2bf(tile[tx][ty + i]);
}

// ---------------- fused Q/K/V projection: one dispatch, grid.z selects ------
__global__ __launch_bounds__(256) void proj_qkv(
    const float* __restrict__ Xq, const float* __restrict__ Xk,
    const float* __restrict__ Xv,
    const u16* __restrict__ Wqt, const u16* __restrict__ Wkt,
    const u16* __restrict__ Wvt,
    const float* __restrict__ bq, const float* __restrict__ bk,
    const float* __restrict__ bv,
    u16* __restrict__ Qp, u16* __restrict__ Kp, u16* __restrict__ Vp,
    float qscale)
{
  constexpr int K = 1024, N = 1024;
  const float* A; const u16* Bt; const float* bias; u16* C; float oscale;
  if (blockIdx.z == 0)      { A = Xq; Bt = Wqt; bias = bq; C = Qp; oscale = qscale; }
  else if (blockIdx.z == 1) { A = Xk; Bt = Wkt; bias = bk; C = Kp; oscale = 1.f; }
  else                      { A = Xv; Bt = Wvt; bias = bv; C = Vp; oscale = 1.f; }

  __shared__ u16 As[128 * 64];   // swizzled
  __shared__ u16 Bs[128 * 64];   // linear (gload_lds dest)
  const int tid = threadIdx.x;
  const int w = tid >> 6;
  const int lane = tid & 63;
  const int lo = lane & 15, hi = lane >> 4;
  const int brow = blockIdx.x * 128;
  const int bcol = blockIdx.y * 128;
  const int wr = (w >> 1) * 64;
  const int wc = (w & 1) * 64;

  f32x4 acc[4][4] = {};

  for (int k0 = 0; k0 < K; k0 += 64) {
    __syncthreads();
    #pragma unroll
    for (int i = 0; i < 4; i++) {
      int c = i * 256 + tid;
      int rowo = c >> 3;
      int ko = (c & 7) * 8;
      gload_lds16(Bt + (size_t)(bcol + rowo) * K + k0 + ko,
                  (void*)(Bs + (size_t)(i * 256 + w * 64) * 8));
    }
    #pragma unroll
    for (int i = 0; i < 4; i++) {
      int c = i * 256 + tid;
      int rowo = c >> 3;
      int ko = (c & 7) * 8;
      const float* Ap = A + (size_t)(brow + rowo) * K + k0 + ko;
      float4 v0 = *(const float4*)Ap;
      float4 v1 = *(const float4*)(Ap + 4);
      u16x8 ab;
      ab[0] = f2bf(v0.x); ab[1] = f2bf(v0.y); ab[2] = f2bf(v0.z); ab[3] = f2bf(v0.w);
      ab[4] = f2bf(v1.x); ab[5] = f2bf(v1.y); ab[6] = f2bf(v1.z); ab[7] = f2bf(v1.w);
      *(u16x8*)(As + swz_off(rowo, ko)) = ab;
    }
    __syncthreads();
    #pragma unroll
    for (int kk = 0; kk < 2; kk++) {
      bf16x8 af[4], bfr[4];
      #pragma unroll
      for (int mi = 0; mi < 4; mi++)
        af[mi] = *(const bf16x8*)(As + swz_off(wr + mi * 16 + lo, kk * 32 + hi * 8));
      #pragma unroll
      for (int ni = 0; ni < 4; ni++)
        bfr[ni] = *(const bf16x8*)(Bs + (wc + ni * 16 + lo) * 64 + kk * 32 + hi * 8);
      #pragma unroll
      for (int mi = 0; mi < 4; mi++)
        #pragma unroll
        for (int ni = 0; ni < 4; ni++)
          acc[mi][ni] = __builtin_amdgcn_mfma_f32_16x16x32_bf16(
              af[mi], bfr[ni], acc[mi][ni], 0, 0, 0);
    }
  }

  #pragma unroll
  for (int mi = 0; mi < 4; mi++)
    #pragma unroll
    for (int ni = 0; ni < 4; ni++) {
      int row = brow + wr + mi * 16 + hi * 4;
      int col = bcol + wc + ni * 16 + lo;
      float bv = bias[col];
      #pragma unroll
      for (int r = 0; r < 4; r++) {
        float v = (acc[mi][ni][r] + bv) * oscale;
        C[(size_t)(row + r) * N + col] = f2bf(v);
      }
    }
}

// ---------------- output projection: C = (A @ Bt^T + bias), fp32 out --------
__global__ __launch_bounds__(256) void gemm_out(
    const u16* __restrict__ A, const u16* __restrict__ Bt,
    const float* __restrict__ bias, float* __restrict__ C)
{
  constexpr int K = 1024, N = 1024;
  __shared__ u16 As[128 * 64];
  __shared__ u16 Bs[128 * 64];
  const int tid = threadIdx.x;
  const int w = tid >> 6;
  const int lane = tid & 63;
  const int lo = lane & 15, hi = lane >> 4;
  const int brow = blockIdx.x * 128;
  const int bcol = blockIdx.y * 128;
  const int wr = (w >> 1) * 64;
  const int wc = (w & 1) * 64;

  f32x4 acc[4][4] = {};

  for (int k0 = 0; k0 < K; k0 += 64) {
    __syncthreads();
    #pragma unroll
    for (int i = 0; i < 4; i++) {
      int c = i * 256 + tid;
      int rowo = c >> 3;
      int ko = (c & 7) * 8;
      gload_lds16(A + (size_t)(brow + rowo) * K + k0 + ko,
                  (void*)(As + (size_t)(i * 256 + w * 64) * 8));
      gload_lds16(Bt + (size_t)(bcol + rowo) * K + k0 + ko,
                  (void*)(Bs + (size_t)(i * 256 + w * 64) * 8));
    }
    __syncthreads();
    #pragma unroll
    for (int kk = 0; kk < 2; kk++) {
      bf16x8 af[4], bfr[4];
      #pragma unroll
      for (int mi = 0; mi < 4; mi++)
        af[mi] = *(const bf16x8*)(As + (wr + mi * 16 + lo) * 64 + kk * 32 + hi * 8);
      #pragma unroll
      for (int ni = 0; ni < 4; ni++)
        bfr[ni] = *(const bf16x8*)(Bs + (wc + ni * 16 + lo) * 64 + kk * 32 + hi * 8);
      #pragma unroll
      for (int mi = 0; mi < 4; mi++)
        #pragma unroll
        for (int ni = 0; ni < 4; ni++)
          acc[mi][ni] = __builtin_amdgcn_mfma_f32_16x16x32_bf16(
              af[mi], bfr[ni], acc[mi][ni], 0, 0, 0);
    }
  }

  #pragma unroll
  for (int mi = 0; mi < 4; mi++)
    #pragma unroll
    for (int ni = 0; ni < 4; ni++) {
      int row = brow + wr + mi * 16 + hi * 4;
      int col = bcol + wc + ni * 16 + lo;
      float bv = bias[col];
      #pragma unroll
      for (int r = 0; r < 4; r++)
        C[(size_t)(row + r) * N + col] = acc[mi][ni][r] + bv;
    }
}

// ---------------- flash attention: no per-iter cross-lane ops ----------------
// Swapped-operand (S^T), exp2 domain, dbuf K/V, 1 barrier/tile.
// Softmax: ballot-only defer-max check (shfl reduce only inside the rare
// rescale branch); lrun kept as per-lane PARTIAL sum, combined across the
// 4 hi-lanes once in the epilogue.
__global__ __launch_bounds__(256) void attn_kernel(
    const u16* __restrict__ Qp, const u16* __restrict__ Kp,
    const u16* __restrict__ Vp, u16* __restrict__ O)
{
  constexpr int Bb = 4, E = 1024, Nn = 2048, Dh = 64;
  constexpr float THR = 8.0f;       // defer-max threshold (log2 units)
  __shared__ u16 Ks[2][64 * 64];    // K tile [n][d], swizzled
  __shared__ u16 Vt[2][64 * 64];    // V^T tile [d][n], swizzled
  __shared__ u16 Ps[4][32 * 64];    // per-wave P tile [m][n], swizzled

  const int tid = threadIdx.x;
  const int lane = tid & 63;
  const int w = tid >> 6;
  const int lo = lane & 15, hi = lane >> 4;

  // XCD-grouping swizzle: blocks sharing (b,h) -> same XCD L2
  const int wg = blockIdx.x;
  const int swz = (wg & 7) * 128 + (wg >> 3);
  const int b_ = swz >> 8;
  const int h = (swz >> 4) & 15;
  const int mbase = (swz & 15) * 128 + w * 32;

  // Q fragments (pre-scaled by 1/sqrt(d)*log2e in projection)
  bf16x8 q[2][2];
  #pragma unroll
  for (int mi = 0; mi < 2; mi++)
    #pragma unroll
    for (int kk = 0; kk < 2; kk++) {
      int m = mbase + mi * 16 + lo;
      q[mi][kk] = *(const bf16x8*)(Qp + (size_t)(m * Bb + b_) * E + h * Dh + kk * 32 + hi * 8);
    }

  f32x4 acc[2][4] = {};
  float mrun[2] = {-3e38f, -3e38f};
  float lrun[2] = {0.f, 0.f};        // per-lane PARTIAL (own 16 n-values)

  // staging assignments
  const int nrK = tid >> 3;            // + i*32
  const int q8K = (tid & 7) * 8;
  const int dq = (tid & 15) * 4;       // V: 4x4 block at (nq.., dq..)
  const int nq = (tid >> 4) * 4;

  // prefetch tile 0
  u16x8 kreg[2];
  u16x4 vreg[4];
  #pragma unroll
  for (int i = 0; i < 2; i++)
    kreg[i] = *(const u16x8*)(Kp + (size_t)((i * 32 + nrK) * Bb + b_) * E + h * Dh + q8K);
  #pragma unroll
  for (int j = 0; j < 4; j++)
    vreg[j] = *(const u16x4*)(Vp + (size_t)((nq + j) * Bb + b_) * E + h * Dh + dq);

  int it = 0;
  for (int n0 = 0; n0 < Nn; n0 += 64, it ^= 1) {
    // stage regs -> LDS buf[it]
    #pragma unroll
    for (int i = 0; i < 2; i++)
      *(u16x8*)(&Ks[it][swz_off(i * 32 + nrK, q8K)]) = kreg[i];
    #pragma unroll
    for (int jw = 0; jw < 4; jw++) {
      u16x4 colv;
      #pragma unroll
      for (int j = 0; j < 4; j++) colv[j] = vreg[j][jw];
      *(u16x4*)(&Vt[it][swz_off(dq + jw, nq)]) = colv;
    }
    __syncthreads();
    // issue next tile's global loads; they retire under compute
    if (n0 + 64 < Nn) {
      #pragma unroll
      for (int i = 0; i < 2; i++)
        kreg[i] = *(const u16x8*)(Kp + (size_t)((n0 + 64 + i * 32 + nrK) * Bb + b_) * E + h * Dh + q8K);
      #pragma unroll
      for (int j = 0; j < 4; j++)
        vreg[j] = *(const u16x4*)(Vp + (size_t)((n0 + 64 + nq + j) * Bb + b_) * E + h * Dh + dq);
    }
    const u16* ksp = &Ks[it][0];
    const u16* vtp = &Vt[it][0];

    // S^T = K Q^T (log2 domain): s[mi][ni][r] = S[n][m=mi*16+lo]
    f32x4 s[2][4];
    __builtin_amdgcn_s_setprio(1);
    #pragma unroll
    for (int ni = 0; ni < 4; ni++) {
      bf16x8 kf0 = *(const bf16x8*)(ksp + swz_off(ni * 16 + lo, hi * 8));
      bf16x8 kf1 = *(const bf16x8*)(ksp + swz_off(ni * 16 + lo, 32 + hi * 8));
      #pragma unroll
      for (int mi = 0; mi < 2; mi++) {
        f32x4 t = {};
        t = __builtin_amdgcn_mfma_f32_16x16x32_bf16(kf0, q[mi][0], t, 0, 0, 0);
        t = __builtin_amdgcn_mfma_f32_16x16x32_bf16(kf1, q[mi][1], t, 0, 0, 0);
        s[mi][ni] = t;
      }
    }
    __builtin_amdgcn_s_setprio(0);

    // lane-local online softmax, zero cross-lane ops on the common path
    #pragma unroll
    for (int mi = 0; mi < 2; mi++) {
      // local 16-max (tree; max3-fusable)
      f32x4 mx4 = s[mi][0];
      #pragma unroll
      for (int ni = 1; ni < 4; ni++) {
        #pragma unroll
        for (int r = 0; r < 4; r++) mx4[r] = fmaxf(mx4[r], s[mi][ni][r]);
      }
      float tm = fmaxf(fmaxf(mx4[0], mx4[1]), fmaxf(mx4[2], mx4[3]));
      // wave-wide check; shfl reduce only inside the rare rescale branch.
      // (mrun is identical across the 4 hi-lanes of a row, so lane-local
      //  comparisons compose into the correct per-row predicate.)
      if (!__all(tm <= mrun[mi] + THR)) {
        float g = fmaxf(tm, __shfl_xor(tm, 16));
        g = fmaxf(g, __shfl_xor(g, 32));
        float mn = fmaxf(mrun[mi], g);
        float al = fast_exp2(mrun[mi] - mn);
        mrun[mi] = mn;
        lrun[mi] *= al;
        #pragma unroll
        for (int df = 0; df < 4; df++) acc[mi][df] *= al;
      }
      const float m_ = mrun[mi];
      f32x4 rv = {0.f, 0.f, 0.f, 0.f};
      #pragma unroll
      for (int ni = 0; ni < 4; ni++) {
        #pragma unroll
        for (int r = 0; r < 4; r++) {
          float p = fast_exp2(s[mi][ni][r] - m_);
          s[mi][ni][r] = p;
          rv[r] += p;
        }
      }
      lrun[mi] += (rv[0] + rv[1]) + (rv[2] + rv[3]);
      #pragma unroll
      for (int ni = 0; ni < 4; ni++) {
        u16x4 pk;
        #pragma unroll
        for (int r = 0; r < 4; r++) pk[r] = f2bf(s[mi][ni][r]);
        *(u16x4*)(Ps[w] + swz_off(mi * 16 + lo, ni * 16 + hi * 4)) = pk;
      }
    }

    // O^T += V^T P
    __builtin_amdgcn_s_setprio(1);
    #pragma unroll
    for (int kk = 0; kk < 2; kk++) {
      bf16x8 pf[2];
      #pragma unroll
      for (int mi = 0; mi < 2; mi++)
        pf[mi] = *(const bf16x8*)(Ps[w] + swz_off(mi * 16 + lo, kk * 32 + hi * 8));
      #pragma unroll
      for (int df = 0; df < 4; df++) {
        bf16x8 vf = *(const bf16x8*)(vtp + swz_off(df * 16 + lo, kk * 32 + hi * 8));
        #pragma unroll
        for (int mi = 0; mi < 2; mi++)
          acc[mi][df] = __builtin_amdgcn_mfma_f32_16x16x32_bf16(vf, pf[mi], acc[mi][df], 0, 0, 0);
      }
    }
    __builtin_amdgcn_s_setprio(0);
  }

  // epilogue: combine lrun partials across the 4 hi-lanes (once), divide, store
  #pragma unroll
  for (int mi = 0; mi < 2; mi++) {
    float l = lrun[mi];
    l += __shfl_xor(l, 16);
    l += __shfl_xor(l, 32);
    float inv = 1.f / l;
    int m = mbase + mi * 16 + lo;
    #pragma unroll
    for (int df = 0; df < 4; df++) {
      u16x4 o;
      #pragma unroll
      for (int r = 0; r < 4; r++) o[r] = f2bf(acc[mi][df][r] * inv);
      *(u16x4*)(O + (size_t)(m * Bb + b_) * E + h * Dh + df * 16 + hi * 4) = o;
    }
  }
}

extern "C" void kernel_launch(void* const* d_in, const int* in_sizes, int n_in,
                              void* d_out, int out_size, void* d_ws, size_t ws_size,
                              hipStream_t stream) {
  const float* query = (const float*)d_in[0];
  const float* key   = (const float*)d_in[1];
  const float* value = (const float*)d_in[2];
  const float* Wq = (const float*)d_in[3];
  const float* bq = (const float*)d_in[4];
  const float* Wk = (const float*)d_in[5];
  const float* bk = (const float*)d_in[6];
  const float* Wv = (const float*)d_in[7];
  const float* bv = (const float*)d_in[8];
  const float* Wo = (const float*)d_in[9];
  const float* bo = (const float*)d_in[10];
  float* out = (float*)d_out;

  const float QSCALE = 0.125f * LOG2E;  // 1/sqrt(64) * log2(e)

  const size_t XE = (size_t)2048 * 4 * 1024;  // M*B*E
  const size_t WE = (size_t)1024 * 1024;
  u16* ws  = (u16*)d_ws;
  u16* Qp  = ws;
  u16* Kp  = Qp + XE;
  u16* Vp  = Kp + XE;
  u16* Ob  = Vp + XE;       // attention output (bf16)
  u16* Wqt = Ob + XE;
  u16* Wkt = Wqt + WE;
  u16* Wvt = Wkt + WE;
  u16* Wot = Wvt + WE;

  dim3 blk(256);
  transpose_cvt4<<<dim3(32, 32, 4), blk, 0, stream>>>(
      Wq, Wk, Wv, Wo, Wqt, Wkt, Wvt, Wot);

  proj_qkv<<<dim3(64, 8, 3), blk, 0, stream>>>(
      query, key, value, Wqt, Wkt, Wvt, bq, bk, bv, Qp, Kp, Vp, QSCALE);

  attn_kernel<<<1024, blk, 0, stream>>>(Qp, Kp, Vp, Ob);

  gemm_out<<<dim3(64, 8), blk, 0, stream>>>(Ob, Wot, bo, out);
}